// Round 13
// baseline (4704.226 us; speedup 1.0000x reference)
//
#include <hip/hip_runtime.h>

typedef _Float16 half2_t __attribute__((ext_vector_type(2)));
typedef __bf16   bf16x8  __attribute__((ext_vector_type(8)));
typedef float    f32x4   __attribute__((ext_vector_type(4)));
typedef unsigned short u16x8 __attribute__((ext_vector_type(8)));
typedef unsigned int  uint32;
typedef unsigned long long uint64;

#define LSTM_N 32
#define LSTM_T 2048
#define LSTM_D 256
#define LSTM_H 256
#define NG 1024
#define CH 256                    // time-chunk length
#define NCH (LSTM_T / CH)         // 8 chunks
#define MCH (LSTM_N * CH)         // 8192 rows per chunk GEMM

// ---- workspace layout (bytes) ---- (~34.6 MB)
#define OFF_XG   ((size_t)0)
#define SZ_XG    ((size_t)MCH * NG * 4)             // 33,554,432 xg chunk f32
#define OFF_WIHB (OFF_XG + SZ_XG)
#define SZ_WIHB  ((size_t)NG * LSTM_D * 2)          // w_ih bf16
#define OFF_BIAS (OFF_WIHB + SZ_WIHB)
#define SZ_BIAS  ((size_t)4096)
#define OFF_WPK  (OFF_BIAS + SZ_BIAS)
#define SZ_WPK   ((size_t)8 * 512 * 32 * 4)         // 524,288 w_hh f16 pairs (eighth-split)
#define OFF_CST  (OFF_WPK + SZ_WPK)
#define SZ_CST   ((size_t)LSTM_N * 256 * 4)         // c state f32
#define OFF_HX   (OFF_CST + SZ_CST)
#define SZ_HX    ((size_t)LSTM_N * 2 * 128 * 8)     // 65,536 board: tagged-u64 unit-pair slots

#if defined(__has_builtin)
#if __has_builtin(__builtin_amdgcn_fdot2)
#define HAVE_FDOT2 1
#endif
#endif

// PROVEN datapath (R2/R3/R6/R8/R9/R12, absmax 0.0078). Inline-asm v_dot2 is
// numerically WRONG on gfx950 (R5/R7 failed identically) - permanently banned.
__device__ __forceinline__ float fdot2(uint32 w, uint32 h, float acc) {
#ifdef HAVE_FDOT2
  return __builtin_amdgcn_fdot2(__builtin_bit_cast(half2_t, w),
                                __builtin_bit_cast(half2_t, h), acc, false);
#else
  half2_t wv = __builtin_bit_cast(half2_t, w);
  half2_t hv = __builtin_bit_cast(half2_t, h);
  float r = fmaf((float)wv.x, (float)hv.x, acc);
  return fmaf((float)wv.y, (float)hv.y, r);
#endif
}

__device__ __forceinline__ float sigm(float x) { return 1.f / (1.f + __expf(-x)); }
__device__ __forceinline__ float tanh_fast(float x) { return 2.f / (1.f + __expf(-2.f * x)) - 1.f; }

__device__ __forceinline__ unsigned short f2bf(float f) {
  uint32 u = __builtin_bit_cast(uint32, f);
  uint32 r = (u + 0x7FFFu + ((u >> 16) & 1u)) >> 16;
  return (unsigned short)r;
}

// ---------------- kernels ----------------

__global__ void cvt_bf16_k(const float* __restrict__ src, unsigned short* __restrict__ dst, int n) {
  int i = blockIdx.x * blockDim.x + threadIdx.x;
  if (4 * i + 3 < n) {
    float4 v = ((const float4*)src)[i];
    ushort4 o;
    o.x = f2bf(v.x); o.y = f2bf(v.y); o.z = f2bf(v.z); o.w = f2bf(v.w);
    ((ushort4*)dst)[i] = o;
  }
}

__global__ void bias_sum_k(const float* __restrict__ bih, const float* __restrict__ bhh,
                           float* __restrict__ bias) {
  int g = blockIdx.x * blockDim.x + threadIdx.x;
  if (g < NG) bias[g] = bih[g] + bhh[g];
}

// Pack w_hh f32[1024][256] -> eighth-split f16-pair images.
// Scan WG-eighth e: units [32e,32e+32) x 4 gates = 128 rows, full k.
// Thread t: r_loc=t>>2 (row), kq=t&3 (k-quarter). wr[m] (m=0..31):
//   row R = (r_loc>>5)*256 + 32e + (r_loc&31), k = 64*kq + 2m.
// Stored so scan's uint4 load wpk4[(e*8+ig)*512+t] is coalesced.
__global__ void wpack_k(const float* __restrict__ whh, uint32* __restrict__ wpk) {
  int idx = blockIdx.x * blockDim.x + threadIdx.x;  // < 131072
  int e = idx >> 14;
  int m = (idx >> 9) & 31;
  int t = idx & 511;
  int r_loc = t >> 2, kq = t & 3;
  int R = (r_loc >> 5) * 256 + 32 * e + (r_loc & 31);
  int k = 64 * kq + 2 * m;
  half2_t h;
  h.x = (_Float16)whh[R * 256 + k];
  h.y = (_Float16)whh[R * 256 + k + 1];
  wpk[((e * 8 + (m >> 2)) * 512 + t) * 4 + (m & 3)] = __builtin_bit_cast(uint32, h);
}

// init carried state + board (every launch -> replay-safe). [R12 verbatim]
// Board per sample: [parity 2][128 unit-pair slots] tagged u64.
// parity0 pre-posted with h0 + tag 0 (step-0 want); parity1 = never-match tag.
__global__ void state_init_k(const float* __restrict__ state, float* __restrict__ cst,
                             uint64* __restrict__ hx) {
  int i = blockIdx.x * blockDim.x + threadIdx.x;  // < 8192
  int n = i >> 8, jj = i & 255;
  cst[i] = state[n * 512 + 256 + jj];
  if (jj < 128) {  // parity0 slot jj: units (2jj, 2jj+1)
    half2_t h2;
    h2.x = (_Float16)state[n * 512 + 2 * jj];
    h2.y = (_Float16)state[n * 512 + 2 * jj + 1];
    hx[(size_t)n * 256 + jj] = (uint64)__builtin_bit_cast(uint32, h2);  // tag 0
  } else {
    hx[(size_t)n * 256 + jj] = 0x8000000000000000ull;  // parity1: never matches
  }
}

// xg[8192][1024] = x(chunk rows, cvt bf16 inline) @ w_ih_bf16^T + bias  [R2/R3 verbatim]
__global__ __launch_bounds__(256) void gemm_xg(const float* __restrict__ x,
                                               const unsigned short* __restrict__ wb,
                                               const float* __restrict__ bias,
                                               float* __restrict__ xg, int ch) {
  __shared__ unsigned short As[128 * 40];  // 80B rows (stride = 5*16B, odd*16)
  __shared__ unsigned short Bs[128 * 40];
  const int tid = threadIdx.x;
  const int m0 = blockIdx.y * 128;
  const int g0 = blockIdx.x * 128;
  const int w = tid >> 6;
  const int lane = tid & 63;
  const int wm = (w >> 1) * 64, wn = (w & 1) * 64;
  const int row_l = tid >> 2;  // 0..63
  const int q = tid & 3;
  const int lr = lane & 15, kg = lane >> 4;

  size_t grow[2];
#pragma unroll
  for (int r = 0; r < 2; ++r) {
    int gm = m0 + row_l + 64 * r;
    grow[r] = (size_t)(gm >> 8) * LSTM_T + (size_t)ch * CH + (gm & 255);
  }

  f32x4 acc[4][4];
#pragma unroll
  for (int i = 0; i < 4; ++i)
#pragma unroll
    for (int j = 0; j < 4; ++j) acc[i][j] = (f32x4){0.f, 0.f, 0.f, 0.f};

  for (int kt = 0; kt < 8; ++kt) {
#pragma unroll
    for (int r = 0; r < 2; ++r) {
      int row = row_l + 64 * r;
      const float* ap = x + grow[r] * 256 + kt * 32 + q * 8;
      float4 v0 = *(const float4*)ap;
      float4 v1 = *(const float4*)(ap + 4);
      u16x8 o;
      o[0] = f2bf(v0.x); o[1] = f2bf(v0.y); o[2] = f2bf(v0.z); o[3] = f2bf(v0.w);
      o[4] = f2bf(v1.x); o[5] = f2bf(v1.y); o[6] = f2bf(v1.z); o[7] = f2bf(v1.w);
      *(uint4*)((char*)As + row * 80 + q * 16) = __builtin_bit_cast(uint4, o);
      uint4 bv = *(const uint4*)(wb + (size_t)(g0 + row) * 256 + kt * 32 + q * 8);
      *(uint4*)((char*)Bs + row * 80 + q * 16) = bv;
    }
    __syncthreads();
    bf16x8 af[4], bfr[4];
#pragma unroll
    for (int i = 0; i < 4; ++i)
      af[i] = __builtin_bit_cast(bf16x8, *(const uint4*)((char*)As + (wm + 16 * i + lr) * 80 + kg * 16));
#pragma unroll
    for (int j = 0; j < 4; ++j)
      bfr[j] = __builtin_bit_cast(bf16x8, *(const uint4*)((char*)Bs + (wn + 16 * j + lr) * 80 + kg * 16));
#pragma unroll
    for (int i = 0; i < 4; ++i)
#pragma unroll
      for (int j = 0; j < 4; ++j)
        acc[i][j] = __builtin_amdgcn_mfma_f32_16x16x32_bf16(af[i], bfr[j], acc[i][j], 0, 0, 0);
    __syncthreads();
  }
#pragma unroll
  for (int j = 0; j < 4; ++j) {
    int gc = g0 + wn + 16 * j + lr;
    float bj = bias[gc];
#pragma unroll
    for (int i = 0; i < 4; ++i) {
#pragma unroll
      for (int r = 0; r < 4; ++r) {
        int m = m0 + wm + 16 * i + kg * 4 + r;
        xg[(size_t)m * NG + gc] = acc[i][j][r] + bj;
      }
    }
  }
}

// Recurrent scan: 128 WGs = 16 sample-pairs x 8 eighths; 2-sample interleave.
// Swizzle puts a pair's 8 WGs on one XCD (perf only). WG (g,e): samples
// nA=2g, nB=2g+1; units [32e,32e+32) x 4 gates = 128 rows, full k=256.
// Thread t: r_loc=t>>2 owns ONE row, kq=t&3 its k-quarter (32 fdot2);
// reduce = 2 shfl_xor. Phase A then phase B per iteration: A's board post
// is consumed one full B-phase later -> exchange latency off the chain.
// Board protocol = R12-proven (tagged u64, parity dbuf, tag s+1, s_sleep).
__global__ __launch_bounds__(512, 1) void lstm_scan(const float* __restrict__ xg,
                                                    const uint4* __restrict__ wpk4,
                                                    float* __restrict__ cst,
                                                    uint64* __restrict__ hx,
                                                    float* __restrict__ out, int ch) {
  __shared__ uint32 hbA[2][128];      // sample-A h board copy (u32 = unit pair)
  __shared__ uint32 hbB[2][128];
  __shared__ float actb[128];         // reused A then B (barrier-separated)
  __shared__ float ostage[2][16][32]; // [phase][step][unit] flushed every 16

  const int b = blockIdx.x;
  const int g = (b & 7) | ((b >> 6) << 3);  // sample-pair 0..15 (XCD = g&7)
  const int e = (b >> 3) & 7;               // eighth 0..7
  const int nA = 2 * g, nB = 2 * g + 1;
  const int t = threadIdx.x;
  const int r_loc = t >> 2, kq = t & 3;
  const int q = r_loc >> 5, u_loc = r_loc & 31;
  const int R = q * 256 + 32 * e + u_loc;   // this lane's global gate-row

  // weights -> 32 regs (shared by both samples)
  uint32 wr[32];
#pragma unroll
  for (int ig = 0; ig < 8; ++ig) {
    uint4 v = wpk4[(e * 8 + ig) * 512 + t];
    wr[4 * ig + 0] = v.x; wr[4 * ig + 1] = v.y; wr[4 * ig + 2] = v.z; wr[4 * ig + 3] = v.w;
  }
  float cA = 0.f, cB = 0.f;
  if (t < 32) {
    cA = cst[nA * 256 + 32 * e + t];
    cB = cst[nB * 256 + 32 * e + t];
  }

  const float* xgA = xg + (size_t)nA * CH * NG;
  const float* xgB = xg + (size_t)nB * CH * NG;
  float* outA = out + ((size_t)nA * LSTM_T + (size_t)ch * CH) * LSTM_H + 32 * e;
  float* outB = out + ((size_t)nB * LSTM_T + (size_t)ch * CH) * LSTM_H + 32 * e;
  uint64* boardA = hx + (size_t)nA * 256;
  uint64* boardB = hx + (size_t)nB * 256;
  const int gsbase = ch * CH;

  for (int tt = 0; tt < CH; ++tt) {
    const int s = gsbase + tt;
    const int par = s & 1;
    // ================= phase A =================
    float xcA = 0.f;
    if (kq == 0) xcA = xgA[(size_t)tt * NG + R];     // early issue, used post-dots
    if (t < 128 && (tt == 0 || (t >> 4) != e)) {     // deposit non-own (all at tt==0)
      uint64* sp = &boardA[(size_t)par * 128 + t];
      uint64 v;
      for (;;) {
        v = __hip_atomic_load(sp, __ATOMIC_RELAXED, __HIP_MEMORY_SCOPE_AGENT);
        if ((uint32)(v >> 32) == (uint32)s) break;
        __builtin_amdgcn_s_sleep(1);
      }
      hbA[par][t] = (uint32)v;
    }
    __syncthreads();                                 // BAR A1: board complete
    {
      const uint4* hb4 = (const uint4*)&hbA[par][32 * kq];
      uint32 hh[32];
#pragma unroll
      for (int i = 0; i < 8; ++i) *(uint4*)&hh[4 * i] = hb4[i];
      float a0 = 0.f, a1 = 0.f;
#pragma unroll
      for (int m = 0; m < 16; ++m) {
        a0 = fdot2(wr[2 * m], hh[2 * m], a0);
        a1 = fdot2(wr[2 * m + 1], hh[2 * m + 1], a1);
      }
      float a = a0 + a1;
      a += __shfl_xor(a, 1, 64);
      a += __shfl_xor(a, 2, 64);
      if (kq == 0) {
        float pre = a + xcA;
        actb[r_loc] = (q == 2) ? tanh_fast(pre) : sigm(pre);
      }
    }
    __syncthreads();                                 // BAR A2: gates ready
    if (t < 32) {                                    // cell A: unit 32e+t
      float gi = actb[t], gf = actb[32 + t], gg = actb[64 + t], go = actb[96 + t];
      cA = gf * cA + gi * gg;
      float h = go * tanh_fast(cA);
      _Float16 hf = (_Float16)h;
      uint32 hz = (uint32)__builtin_bit_cast(unsigned short, hf);
      ((unsigned short*)&hbA[par ^ 1][0])[32 * e + t] = (unsigned short)hz;
      ostage[0][tt & 15][t] = h;
      uint32 hn = (uint32)__shfl_xor((int)hz, 1, 64);
      if ((t & 1) == 0) {                            // post pair, tag s+1 (always)
        uint64 msg = (uint64)(hz | (hn << 16)) | ((uint64)(uint32)(s + 1) << 32);
        __hip_atomic_store(&boardA[(size_t)((s + 1) & 1) * 128 + 16 * e + (t >> 1)],
                           msg, __ATOMIC_RELAXED, __HIP_MEMORY_SCOPE_AGENT);
      }
      if (ch == NCH - 1 && tt == CH - 1) {
        float* os = out + (size_t)LSTM_N * LSTM_T * LSTM_H + nA * 512;
        os[32 * e + t] = h;
        os[256 + 32 * e + t] = cA;
      }
    }
    // ================= phase B ================= (A's post hides under this)
    float xcB = 0.f;
    if (kq == 0) xcB = xgB[(size_t)tt * NG + R];
    if (t < 128 && (tt == 0 || (t >> 4) != e)) {
      uint64* sp = &boardB[(size_t)par * 128 + t];
      uint64 v;
      for (;;) {
        v = __hip_atomic_load(sp, __ATOMIC_RELAXED, __HIP_MEMORY_SCOPE_AGENT);
        if ((uint32)(v >> 32) == (uint32)s) break;
        __builtin_amdgcn_s_sleep(1);
      }
      hbB[par][t] = (uint32)v;
    }
    __syncthreads();                                 // BAR B1
    {
      const uint4* hb4 = (const uint4*)&hbB[par][32 * kq];
      uint32 hh[32];
#pragma unroll
      for (int i = 0; i < 8; ++i) *(uint4*)&hh[4 * i] = hb4[i];
      float a0 = 0.f, a1 = 0.f;
#pragma unroll
      for (int m = 0; m < 16; ++m) {
        a0 = fdot2(wr[2 * m], hh[2 * m], a0);
        a1 = fdot2(wr[2 * m + 1], hh[2 * m + 1], a1);
      }
      float a = a0 + a1;
      a += __shfl_xor(a, 1, 64);
      a += __shfl_xor(a, 2, 64);
      if (kq == 0) {
        float pre = a + xcB;
        actb[r_loc] = (q == 2) ? tanh_fast(pre) : sigm(pre);
      }
    }
    __syncthreads();                                 // BAR B2
    if (t < 32) {                                    // cell B
      float gi = actb[t], gf = actb[32 + t], gg = actb[64 + t], go = actb[96 + t];
      cB = gf * cB + gi * gg;
      float h = go * tanh_fast(cB);
      _Float16 hf = (_Float16)h;
      uint32 hz = (uint32)__builtin_bit_cast(unsigned short, hf);
      ((unsigned short*)&hbB[par ^ 1][0])[32 * e + t] = (unsigned short)hz;
      ostage[1][tt & 15][t] = h;
      uint32 hn = (uint32)__shfl_xor((int)hz, 1, 64);
      if ((t & 1) == 0) {
        uint64 msg = (uint64)(hz | (hn << 16)) | ((uint64)(uint32)(s + 1) << 32);
        __hip_atomic_store(&boardB[(size_t)((s + 1) & 1) * 128 + 16 * e + (t >> 1)],
                           msg, __ATOMIC_RELAXED, __HIP_MEMORY_SCOPE_AGENT);
      }
      if (ch == NCH - 1 && tt == CH - 1) {
        float* os = out + (size_t)LSTM_N * LSTM_T * LSTM_H + nB * 512;
        os[32 * e + t] = h;
        os[256 + 32 * e + t] = cB;
      }
    }
    if ((tt & 15) == 15) {                           // flush 16 steps, both samples
      __syncthreads();                               // ostage complete (incl cell B)
      if (t < 256) {
        int ph = t >> 7, r = t & 127;
        int sl = r >> 3, li = r & 7;
        float4 v = *(const float4*)&ostage[ph][sl][4 * li];
        float* ob = ph ? outB : outA;
        *(float4*)&ob[(size_t)(tt - 15 + sl) * LSTM_H + 4 * li] = v;
      }
    }
  }
  // persist carried c (h carries over via the board posts)
  if (t < 32) {
    cst[nA * 256 + 32 * e + t] = cA;
    cst[nB * 256 + 32 * e + t] = cB;
  }
}

extern "C" void kernel_launch(void* const* d_in, const int* in_sizes, int n_in,
                              void* d_out, int out_size, void* d_ws, size_t ws_size,
                              hipStream_t stream) {
  const float* x   = (const float*)d_in[0];
  const float* st  = (const float*)d_in[1];
  const float* wih = (const float*)d_in[2];
  const float* whh = (const float*)d_in[3];
  const float* bih = (const float*)d_in[4];
  const float* bhh = (const float*)d_in[5];
  float* out = (float*)d_out;
  char* ws = (char*)d_ws;

  float* xg = (float*)(ws + OFF_XG);
  unsigned short* wihb = (unsigned short*)(ws + OFF_WIHB);
  float* bias = (float*)(ws + OFF_BIAS);
  uint32* wpk = (uint32*)(ws + OFF_WPK);
  float* cst = (float*)(ws + OFF_CST);
  uint64* hx = (uint64*)(ws + OFF_HX);

  cvt_bf16_k<<<(NG * LSTM_D / 4 + 255) / 256, 256, 0, stream>>>(wih, wihb, NG * LSTM_D);
  bias_sum_k<<<4, 256, 0, stream>>>(bih, bhh, bias);
  wpack_k<<<512, 256, 0, stream>>>(whh, wpk);
  state_init_k<<<32, 256, 0, stream>>>(st, cst, hx);

  for (int ch = 0; ch < NCH; ++ch) {
    gemm_xg<<<dim3(NG / 128, MCH / 128), 256, 0, stream>>>(x, wihb, bias, xg, ch);
    lstm_scan<<<128, 512, 0, stream>>>(xg, (const uint4*)wpk, cst, hx, out, ch);
  }
}